// Round 16
// baseline (166.909 us; speedup 1.0000x reference)
//
#include <hip/hip_runtime.h>
#include <math.h>

#define BATCH 16
#define KCLS  19
#define CCH   512
#define HW    16384

#define KSPLIT 16
#define KB     (HW / KSPLIT)   // 1024 k-range per block
#define BK     64              // k per chunk
#define NCHUNK (KB / BK)       // 16
#define OUTN   (BATCH * CCH * KCLS)   // 155648

typedef __attribute__((ext_vector_type(8))) short  short8;
typedef __attribute__((ext_vector_type(4))) float  floatx4;

// fp32 -> bf16 round-to-nearest-even, branchless bit-twiddle (champion r8/r12;
// native cast (+NaN selects) and inline-asm cvt_pk both measured slower, r11/r13)
static __device__ __forceinline__ ushort f2bf(float x) {
  unsigned u = __float_as_uint(x);
  return (ushort)((u + 0x7FFFu + ((u >> 16) & 1u)) >> 16);
}

static __device__ __forceinline__ short8 pack8(floatx4 a, floatx4 b) {
  short8 v;
  v[0] = (short)f2bf(a[0]); v[1] = (short)f2bf(a[1]);
  v[2] = (short)f2bf(a[2]); v[3] = (short)f2bf(a[3]);
  v[4] = (short)f2bf(b[0]); v[5] = (short)f2bf(b[1]);
  v[6] = (short)f2bf(b[2]); v[7] = (short)f2bf(b[3]);
  return v;
}

// ---------------- Kernel B: barrier-free MFMA GEMM, fused sumexp, atomic out ----------------
// r15 structure (block=1024 thr / 16 waves, grid 16x16=256 = 1 block/CU, probs
// read once, A-panel = unnormalized bf16(exp(p)), fused per-(b,k,ks) sumexp to
// pws). CHANGE vs r15: epilogue atomicAdds straight into out (0.6 MB, L2-resident
// RMW) instead of a 10.5 MB partials buffer -> -21 MB HBM round-trip; the
// cross-ks normalization moves to a micro normalize kernel.
struct FSet { floatx4 v[8]; };   // one chunk's F fragments (constant-indexed only)

__global__ __launch_bounds__(1024, 2) void gather_mfma(
    const float* __restrict__ feat, const float* __restrict__ probs,
    float* __restrict__ pws, float* __restrict__ out) {
  __shared__ __align__(16) short A_all[KCLS][KB];   // 38 KB bf16 exp(p) panel
  __shared__ float red[KCLS][4];                    // per-row quarter sums

  const int bid = blockIdx.x;
  const int b   = bid & 15;
  const int ks  = bid >> 4;          // 0..15 (K split)
  const int k0  = ks * KB;

  const int tid  = threadIdx.x;
  const int wave = tid >> 6;         // 16 waves, each owns 32 channels
  const int lane = tid & 63;

  const float* fbase = feat  + ((size_t)b * CCH) * HW + k0;
  const float* pbase = probs + ((size_t)b * KCLS) * HW + k0;

  // per-lane F fragment pointers: two channel rows, k-offset (lane>>4)*8
  const int ch0 = wave * 32 + (lane & 15);
  const int ch1 = ch0 + 16;
  const float* fptr0 = fbase + (size_t)ch0 * HW + (lane >> 4) * 8;
  const float* fptr1 = fbase + (size_t)ch1 * HW + (lane >> 4) * 8;

  floatx4 acc00 = {0,0,0,0}, acc01 = {0,0,0,0}, acc10 = {0,0,0,0}, acc11 = {0,0,0,0};

  FSet sA, sB;

  // fragments for chunk c: kt in {0,1}; v[kt*4+{0,1}] = ch0 lo/hi, v[kt*4+{2,3}] = ch1
#define LOADF(S, c)                                                             \
  {                                                                             \
    const int cb = (c) * BK;                                                    \
    S.v[0] = *(const floatx4*)(fptr0 + cb);                                     \
    S.v[1] = *(const floatx4*)(fptr0 + cb + 4);                                 \
    S.v[2] = *(const floatx4*)(fptr1 + cb);                                     \
    S.v[3] = *(const floatx4*)(fptr1 + cb + 4);                                 \
    S.v[4] = *(const floatx4*)(fptr0 + cb + 32);                                \
    S.v[5] = *(const floatx4*)(fptr0 + cb + 36);                                \
    S.v[6] = *(const floatx4*)(fptr1 + cb + 32);                                \
    S.v[7] = *(const floatx4*)(fptr1 + cb + 36);                                \
  }

  // A granule (16B = 8 bf16): logical g = c*8 + kt*4 + (lane>>4); phys = g ^ (row&7)
#define GEMMC(S, c)                                                             \
  {                                                                             \
    const char* Ab = (const char*)A_all;                                        \
    const int rm0  = lane & 15;                                                 \
    const int rm1  = 16 + (rm0 < 3 ? rm0 : 2);   /* clamp: rows 16..18 valid */ \
    _Pragma("unroll")                                                           \
    for (int kt = 0; kt < 2; kt++) {                                            \
      const int g = (c) * 8 + kt * 4 + (lane >> 4);                             \
      short8 a0 = *(const short8*)(Ab + rm0 * 2048 + ((g ^ (rm0 & 7)) << 4));   \
      short8 a1 = *(const short8*)(Ab + rm1 * 2048 + ((g ^ (rm1 & 7)) << 4));   \
      short8 b0 = pack8(S.v[kt * 4 + 0], S.v[kt * 4 + 1]);                      \
      short8 b1 = pack8(S.v[kt * 4 + 2], S.v[kt * 4 + 3]);                      \
      acc00 = __builtin_amdgcn_mfma_f32_16x16x32_bf16(a0, b0, acc00, 0, 0, 0);  \
      acc01 = __builtin_amdgcn_mfma_f32_16x16x32_bf16(a0, b1, acc01, 0, 0, 0);  \
      acc10 = __builtin_amdgcn_mfma_f32_16x16x32_bf16(a1, b0, acc10, 0, 0, 0);  \
      acc11 = __builtin_amdgcn_mfma_f32_16x16x32_bf16(a1, b1, acc11, 0, 0, 0);  \
    }                                                                           \
  }

  // issue chunk-0 F loads first (in flight during A staging)
  LOADF(sA, 0);

  // ---- stage the A panel (unnormalized exp) + per-row sumexp ----
  // pass p, wave w: row j = 4p + (w>>2) is CONSTANT per (p,wave); quarter = w&3.
  #pragma unroll
  for (int p = 0; p < 5; p++) {
    const int idx = p * 1024 + tid;
    if (idx < KCLS * 256) {
      const int j = idx >> 8;          // class row (wave-uniform)
      const int t = idx & 255;         // float4 column
      float4 pp = *(const float4*)(pbase + (size_t)j * HW + t * 4);
      float e0 = __expf(pp.x), e1 = __expf(pp.y);
      float e2 = __expf(pp.z), e3 = __expf(pp.w);
      unsigned long long w64 =
          (unsigned long long)f2bf(e0) | ((unsigned long long)f2bf(e1) << 16) |
          ((unsigned long long)f2bf(e2) << 32) | ((unsigned long long)f2bf(e3) << 48);
      // logical granule t>>1, half t&1; phys granule XOR row&7
      *(unsigned long long*)((char*)A_all + j * 2048 +
                             (((t >> 1) ^ (j & 7)) << 4) + (t & 1) * 8) = w64;
      float s = (e0 + e1) + (e2 + e3);
      for (int off = 32; off > 0; off >>= 1) s += __shfl_xor(s, off);
      if (lane == 0) red[j][wave & 3] = s;
    }
  }
  __syncthreads();   // the only block-wide barrier

  if (tid < KCLS)
    pws[(b * KCLS + tid) * KSPLIT + ks] =
        (red[tid][0] + red[tid][1]) + (red[tid][2] + red[tid][3]);

  // ---- barrier-free main loop, 2-deep register pipeline ----
  for (int c = 0; c < NCHUNK; c += 2) {
    LOADF(sB, c + 1);
    GEMMC(sA, c);
    if (c + 2 < NCHUNK) LOADF(sA, c + 2);
    GEMMC(sB, c + 1);
  }

  // ---- epilogue: atomicAdd unnormalized sums into out (L2-resident RMW) ----
  // C/D layout: col = lane&15 (channel), row = (lane>>4)*4 + j (class).
  // acc10/acc11 rows valid only for A-tile rows 0..2 (classes 16..18): rb==0, j<3.
  {
    const int chb = wave * 32;
    const int cl  = lane & 15;
    const int rb  = (lane >> 4) * 4;
    float* o0 = out + ((size_t)b * CCH + chb + cl) * KCLS;
    float* o1 = o0 + 16 * KCLS;
    #pragma unroll
    for (int j = 0; j < 4; j++) {
      atomicAdd(o0 + rb + j, acc00[j]);
      atomicAdd(o1 + rb + j, acc01[j]);
    }
    if (rb == 0) {
      #pragma unroll
      for (int j = 0; j < 3; j++) {
        atomicAdd(o0 + 16 + j, acc10[j]);
        atomicAdd(o1 + 16 + j, acc11[j]);
      }
    }
  }
#undef LOADF
#undef GEMMC
}

// ---------------- Kernel C: normalize out by assembled sum(exp) ----------------
__global__ __launch_bounds__(256) void normalize_kernel(
    const float* __restrict__ pws, float* __restrict__ out) {
  const int gid = blockIdx.x * 256 + threadIdx.x;
  if (gid < OUTN) {
    const int bc = gid / KCLS;       // gid = bc*19 + r
    const int r  = gid - bc * KCLS;
    const int b  = bc >> 9;
    float se = 0.f;
    #pragma unroll
    for (int k = 0; k < KSPLIT; k++)
      se += pws[(b * KCLS + r) * KSPLIT + k];   // 19 KB table, L1-hot
    out[gid] /= se;
  }
}

extern "C" void kernel_launch(void* const* d_in, const int* in_sizes, int n_in,
                              void* d_out, int out_size, void* d_ws, size_t ws_size,
                              hipStream_t stream) {
  const float* feat  = (const float*)d_in[0];   // [16, 512, 128, 128] f32
  const float* probs = (const float*)d_in[1];   // [16, 19, 128, 128] f32
  float* out = (float*)d_out;                   // [16, 512, 19, 1] f32
  float* pws = (float*)d_ws;                    // [304][16] sumexp partials

  // atomics accumulate into out -> zero it every call (harness poisons 0xAA)
  hipMemsetAsync(d_out, 0, (size_t)out_size * sizeof(float), stream);

  gather_mfma<<<BATCH * KSPLIT, 1024, 0, stream>>>(feat, probs, pws, out);
  normalize_kernel<<<(OUTN + 255) / 256, 256, 0, stream>>>(pws, out);
}

// Round 17
// 121.394 us; speedup vs baseline: 1.3749x; 1.3749x over previous
//
#include <hip/hip_runtime.h>
#include <math.h>

#define BATCH 16
#define KCLS  19
#define CCH   512
#define HW    16384

#define KSPLIT 16
#define KB     (HW / KSPLIT)   // 1024 k-range per block
#define BK     64              // k per chunk
#define NCHUNK (KB / BK)       // 16
#define KPAD   20
#define BCN    (BATCH * CCH)   // 8192

typedef __attribute__((ext_vector_type(8))) short  short8;
typedef __attribute__((ext_vector_type(4))) float  floatx4;

// fp32 -> bf16 round-to-nearest-even, branchless bit-twiddle (champion r8/r12;
// native cast (+NaN selects) and inline-asm cvt_pk both measured slower, r11/r13)
static __device__ __forceinline__ ushort f2bf(float x) {
  unsigned u = __float_as_uint(x);
  return (ushort)((u + 0x7FFFu + ((u >> 16) & 1u)) >> 16);
}

static __device__ __forceinline__ short8 pack8(floatx4 a, floatx4 b) {
  short8 v;
  v[0] = (short)f2bf(a[0]); v[1] = (short)f2bf(a[1]);
  v[2] = (short)f2bf(a[2]); v[3] = (short)f2bf(a[3]);
  v[4] = (short)f2bf(b[0]); v[5] = (short)f2bf(b[1]);
  v[6] = (short)f2bf(b[2]); v[7] = (short)f2bf(b[3]);
  return v;
}

// ---------------- Kernel B: barrier-free MFMA GEMM, fused sumexp, 1 block/(b,ks) ----------------
// r15 CHAMPION (121.6 us) — exact revert of the r16 atomic-epilogue experiment
// (same-address L2 RMW serialization cost +45 us; partials+reduce costs ~4).
// A-panel = bf16(exp(p)) UN-normalized (N(0,1) -> exp <= ~250, bf16-safe).
// Per-(b,k,ks) sum(exp) computed during staging; reduce kernel divides.
// Block = 1024 thr (16 waves), grid 16x16 = 256 = 1 block/CU; probs read once.
// launch_bounds(1024,2) -> 128-VGPR cap (empirical: 2nd arg w -> cap 256/w).
struct FSet { floatx4 v[8]; };   // one chunk's F fragments (constant-indexed only)

__global__ __launch_bounds__(1024, 2) void gather_mfma(
    const float* __restrict__ feat, const float* __restrict__ probs,
    float* __restrict__ pws, float* __restrict__ part) {
  __shared__ __align__(16) short A_all[KCLS][KB];   // 38 KB bf16 exp(p) panel
  __shared__ float red[KCLS][4];                    // per-row quarter sums

  const int bid = blockIdx.x;
  const int b   = bid & 15;          // bid%8 = b%8 -> batch pinned to one XCD
  const int ks  = bid >> 4;          // 0..15 (K split)
  const int k0  = ks * KB;

  const int tid  = threadIdx.x;
  const int wave = tid >> 6;         // 16 waves, each owns 32 channels
  const int lane = tid & 63;

  const float* fbase = feat  + ((size_t)b * CCH) * HW + k0;
  const float* pbase = probs + ((size_t)b * KCLS) * HW + k0;

  // per-lane F fragment pointers: two channel rows, k-offset (lane>>4)*8
  const int ch0 = wave * 32 + (lane & 15);
  const int ch1 = ch0 + 16;
  const float* fptr0 = fbase + (size_t)ch0 * HW + (lane >> 4) * 8;
  const float* fptr1 = fbase + (size_t)ch1 * HW + (lane >> 4) * 8;

  floatx4 acc00 = {0,0,0,0}, acc01 = {0,0,0,0}, acc10 = {0,0,0,0}, acc11 = {0,0,0,0};

  FSet sA, sB;

  // fragments for chunk c: kt in {0,1}; v[kt*4+{0,1}] = ch0 lo/hi, v[kt*4+{2,3}] = ch1
#define LOADF(S, c)                                                             \
  {                                                                             \
    const int cb = (c) * BK;                                                    \
    S.v[0] = *(const floatx4*)(fptr0 + cb);                                     \
    S.v[1] = *(const floatx4*)(fptr0 + cb + 4);                                 \
    S.v[2] = *(const floatx4*)(fptr1 + cb);                                     \
    S.v[3] = *(const floatx4*)(fptr1 + cb + 4);                                 \
    S.v[4] = *(const floatx4*)(fptr0 + cb + 32);                                \
    S.v[5] = *(const floatx4*)(fptr0 + cb + 36);                                \
    S.v[6] = *(const floatx4*)(fptr1 + cb + 32);                                \
    S.v[7] = *(const floatx4*)(fptr1 + cb + 36);                                \
  }

  // A granule (16B = 8 bf16): logical g = c*8 + kt*4 + (lane>>4); phys = g ^ (row&7)
#define GEMMC(S, c)                                                             \
  {                                                                             \
    const char* Ab = (const char*)A_all;                                        \
    const int rm0  = lane & 15;                                                 \
    const int rm1  = 16 + (rm0 < 3 ? rm0 : 2);   /* clamp: rows 16..18 valid */ \
    _Pragma("unroll")                                                           \
    for (int kt = 0; kt < 2; kt++) {                                            \
      const int g = (c) * 8 + kt * 4 + (lane >> 4);                             \
      short8 a0 = *(const short8*)(Ab + rm0 * 2048 + ((g ^ (rm0 & 7)) << 4));   \
      short8 a1 = *(const short8*)(Ab + rm1 * 2048 + ((g ^ (rm1 & 7)) << 4));   \
      short8 b0 = pack8(S.v[kt * 4 + 0], S.v[kt * 4 + 1]);                      \
      short8 b1 = pack8(S.v[kt * 4 + 2], S.v[kt * 4 + 3]);                      \
      acc00 = __builtin_amdgcn_mfma_f32_16x16x32_bf16(a0, b0, acc00, 0, 0, 0);  \
      acc01 = __builtin_amdgcn_mfma_f32_16x16x32_bf16(a0, b1, acc01, 0, 0, 0);  \
      acc10 = __builtin_amdgcn_mfma_f32_16x16x32_bf16(a1, b0, acc10, 0, 0, 0);  \
      acc11 = __builtin_amdgcn_mfma_f32_16x16x32_bf16(a1, b1, acc11, 0, 0, 0);  \
    }                                                                           \
  }

  // issue chunk-0 F loads first (in flight during A staging)
  LOADF(sA, 0);

  // ---- stage the A panel (unnormalized exp) + per-row sumexp ----
  // pass p, wave w: idx in [p*1024 + w*64, +64) -> row j = 4p + (w>>2) is
  // CONSTANT per (p,wave); quarter = w&3. 5 passes cover 19*256 items.
  #pragma unroll
  for (int p = 0; p < 5; p++) {
    const int idx = p * 1024 + tid;
    if (idx < KCLS * 256) {
      const int j = idx >> 8;          // class row (wave-uniform)
      const int t = idx & 255;         // float4 column
      float4 pp = *(const float4*)(pbase + (size_t)j * HW + t * 4);
      float e0 = __expf(pp.x), e1 = __expf(pp.y);
      float e2 = __expf(pp.z), e3 = __expf(pp.w);
      unsigned long long w64 =
          (unsigned long long)f2bf(e0) | ((unsigned long long)f2bf(e1) << 16) |
          ((unsigned long long)f2bf(e2) << 32) | ((unsigned long long)f2bf(e3) << 48);
      // logical granule t>>1, half t&1; phys granule XOR row&7
      *(unsigned long long*)((char*)A_all + j * 2048 +
                             (((t >> 1) ^ (j & 7)) << 4) + (t & 1) * 8) = w64;
      float s = (e0 + e1) + (e2 + e3);
      for (int off = 32; off > 0; off >>= 1) s += __shfl_xor(s, off);
      if (lane == 0) red[j][wave & 3] = s;
    }
  }
  __syncthreads();   // the only block-wide barrier

  if (tid < KCLS)
    pws[(b * KCLS + tid) * KSPLIT + ks] =
        (red[tid][0] + red[tid][1]) + (red[tid][2] + red[tid][3]);

  // ---- barrier-free main loop, 2-deep register pipeline ----
  for (int c = 0; c < NCHUNK; c += 2) {
    LOADF(sB, c + 1);
    GEMMC(sA, c);
    if (c + 2 < NCHUNK) LOADF(sA, c + 2);
    GEMMC(sB, c + 1);
  }

  // ---- epilogue: partials, plain float4 stores ----
  // C/D layout: col = lane&15 (channel), row = (lane>>4)*4 + j (class)
  {
    const int chb = wave * 32;
    const int cl  = lane & 15;
    const int rb  = (lane >> 4) * 4;
    size_t bc0 = (size_t)b * CCH + chb + cl;
    size_t bc1 = bc0 + 16;
    float* p0 = part + ((size_t)ks * BCN + bc0) * KPAD + rb;
    float* p1 = part + ((size_t)ks * BCN + bc1) * KPAD + rb;
    *(floatx4*)p0 = acc00;
    *(floatx4*)p1 = acc01;
    if (rb == 0) {
      *(floatx4*)(p0 + 16) = acc10;   // classes 16..18 (+pad 19)
      *(floatx4*)(p1 + 16) = acc11;
    }
  }
#undef LOADF
#undef GEMMC
}

// ---------------- Kernel C: reduce partials over KSPLIT + normalize ----------------
__global__ __launch_bounds__(256) void reduce_kernel(
    const float* __restrict__ part, const float* __restrict__ pws,
    float* __restrict__ out) {
  const int gid = blockIdx.x * 256 + threadIdx.x;   // < BCN*KPAD = 163840
  const int bc = gid / KPAD, r = gid - bc * KPAD;
  if (r < KCLS) {
    const int b = bc >> 9;                          // bc = b*512 + c
    float se = 0.f;
    #pragma unroll
    for (int k = 0; k < KSPLIT; k++)
      se += pws[(b * KCLS + r) * KSPLIT + k];       // 19 KB table, L2-hot
    float s = 0.f;
    #pragma unroll
    for (int k = 0; k < KSPLIT; k++)
      s += part[(size_t)k * (BCN * KPAD) + gid];
    out[(size_t)bc * KCLS + r] = s / se;
  }
}

extern "C" void kernel_launch(void* const* d_in, const int* in_sizes, int n_in,
                              void* d_out, int out_size, void* d_ws, size_t ws_size,
                              hipStream_t stream) {
  const float* feat  = (const float*)d_in[0];   // [16, 512, 128, 128] f32
  const float* probs = (const float*)d_in[1];   // [16, 19, 128, 128] f32
  float* out  = (float*)d_out;                  // [16, 512, 19, 1] f32
  float* pws  = (float*)d_ws;                   // [304][16] sumexp partials
  float* part = (float*)((char*)d_ws + 32768);  // [16][8192][20] = 10.5 MB

  gather_mfma<<<BATCH * KSPLIT, 1024, 0, stream>>>(feat, probs, pws, part);
  reduce_kernel<<<(BCN * KPAD) / 256, 256, 0, stream>>>(part, pws, out);
}